// Round 1
// baseline (1087.848 us; speedup 1.0000x reference)
//
#include <hip/hip_runtime.h>
#include <stdint.h>

// GPTQ (4-bit, group=128) dequant GEMM + rank-16 LoRA, fused epilogue.
// Strategy: split-precision bf16 MFMA (x = x_hi + x_lo), weights as exact
// bf16(q-z), group scale applied at accumulator level every 128 K.
// Main GEMM: m97-verified structure (128x128 tile, BK=32, global_load_lds).

#define GM 8192      // B*S
#define GN 4096      // D_out
#define GK 4096      // D_in
#define NGROUPS 32   // GK/128
#define RLORA 16
#define LSCALE 2.0f  // lora_alpha / r = 32/16

typedef __attribute__((ext_vector_type(4))) float f32x4;
typedef __attribute__((ext_vector_type(8))) __bf16 bf16x8;
typedef __attribute__((ext_vector_type(8))) uint16_t u16x8;
typedef __attribute__((ext_vector_type(4))) uint16_t u16x4;

__device__ __forceinline__ uint16_t f2bf(float f) {
  uint32_t u = __float_as_uint(f);
  u += 0x7FFFu + ((u >> 16) & 1u);   // RNE
  return (uint16_t)(u >> 16);
}
__device__ __forceinline__ float bf2f(uint16_t h) {
  return __uint_as_float(((uint32_t)h) << 16);
}

__device__ __forceinline__ void async16(const void* g, void* l) {
  __builtin_amdgcn_global_load_lds(
      (const __attribute__((address_space(1))) void*)g,
      (__attribute__((address_space(3))) void*)l, 16, 0, 0);
}

// ---------------- prepass: x -> x_hi, x_lo (bf16 split) ----------------
__global__ void prep_x_k(const float* __restrict__ x, uint16_t* __restrict__ xh,
                         uint16_t* __restrict__ xl) {
  const int n4 = GM * GK / 4;
  int stride = gridDim.x * blockDim.x;
  for (int i = blockIdx.x * blockDim.x + threadIdx.x; i < n4; i += stride) {
    f32x4 v = ((const f32x4*)x)[i];
    u16x4 h, l;
#pragma unroll
    for (int j = 0; j < 4; ++j) {
      uint16_t hh = f2bf(v[j]);
      h[j] = hh;
      l[j] = f2bf(v[j] - bf2f(hh));
    }
    ((u16x4*)xh)[i] = h;
    ((u16x4*)xl)[i] = l;
  }
}

// ------- prepass: qweight [K][N] -> WqT [N][K] bf16, value (q - z) -------
__global__ void prep_w_k(const int* __restrict__ qw, const int* __restrict__ qz,
                         uint16_t* __restrict__ wt) {
  __shared__ uint16_t t[64][66];   // pad 2 -> stride 132B, conflict-free cols
  int bn = blockIdx.x % (GN / 64);
  int bk = blockIdx.x / (GN / 64);
  int k0 = bk * 64, n0 = bn * 64;
  int g = k0 >> 7;                 // 64-tile never crosses a 128-group
  int tid = threadIdx.x;
  int n = tid & 63;
  int kb = tid >> 6;               // 0..3
  int z = qz[g * GN + n0 + n];
#pragma unroll
  for (int i = 0; i < 16; ++i) {
    int kk = kb + i * 4;
    int q = qw[(size_t)(k0 + kk) * GN + n0 + n];
    t[kk][n] = f2bf((float)(q - z));   // |q-z| <= 15 -> exact in bf16
  }
  __syncthreads();
  for (int c = tid; c < 512; c += 256) {
    int nn = c >> 3;
    int k8 = (c & 7) * 8;
    u16x8 v;
#pragma unroll
    for (int j = 0; j < 8; ++j) v[j] = t[k8 + j][nn];
    *(u16x8*)&wt[(size_t)(n0 + nn) * GK + k0 + k8] = v;
  }
}

// ---------------- LoRA: ax[m][r] = sum_k x[m][k] * A[r][k] ----------------
__global__ void lora_ax_k(const float* __restrict__ x, const float* __restrict__ lA,
                          float* __restrict__ ax) {
  int w = threadIdx.x >> 6, lane = threadIdx.x & 63;
  int m = blockIdx.x * 4 + w;
  const float* xr = x + (size_t)m * GK;
  float acc[RLORA];
#pragma unroll
  for (int r = 0; r < RLORA; ++r) acc[r] = 0.f;
  for (int kb = 0; kb < GK; kb += 256) {
    f32x4 xv = *(const f32x4*)&xr[kb + lane * 4];
#pragma unroll
    for (int r = 0; r < RLORA; ++r) {
      f32x4 av = *(const f32x4*)&lA[(size_t)r * GK + kb + lane * 4];
      f32x4 p = xv * av;
      acc[r] += p[0] + p[1] + p[2] + p[3];
    }
  }
#pragma unroll
  for (int r = 0; r < RLORA; ++r) {
#pragma unroll
    for (int off = 32; off > 0; off >>= 1)
      acc[r] += __shfl_xor(acc[r], off);
  }
  if (lane == 0) {
#pragma unroll
    for (int r = 0; r < RLORA; ++r) ax[m * RLORA + r] = acc[r];
  }
}

// ---------------- main GEMM: (x_hi+x_lo) . Wq, group-scaled, LoRA fused ----------------
__global__ __launch_bounds__(256, 2) void gemm_k(
    const uint16_t* __restrict__ xh, const uint16_t* __restrict__ xl,
    const uint16_t* __restrict__ wt, const float* __restrict__ sc,
    const float* __restrict__ axw, const float* __restrict__ lB,
    float* __restrict__ out) {
  __shared__ __align__(16) uint16_t sAh[128 * 32];
  __shared__ __align__(16) uint16_t sAl[128 * 32];
  __shared__ __align__(16) uint16_t sB[128 * 32];

  const int nbx = GN / 128;               // 32
  const int nwg = (GM / 128) * nbx;       // 2048 (div by 8 -> simple swizzle ok)
  int wg = blockIdx.x;
  int swz = (wg & 7) * (nwg >> 3) + (wg >> 3);   // XCD-bijective swizzle
  int by = swz / nbx, bx = swz % nbx;
  int m0 = by * 128, n0 = bx * 128;

  int tid = threadIdx.x;
  int w = tid >> 6, lane = tid & 63;
  int wm = w >> 1, wn = w & 1;            // 2x2 wave grid, 64x64 per wave
  int fr = lane & 15, fk = lane >> 4;     // fragment row / k-chunk

  int c0 = w * 128 + lane;                // staging chunk id (+j*64)
  int lds0 = w * 1024;                    // ushort offset of wave's LDS span

  f32x4 accf[4][4];
#pragma unroll
  for (int a = 0; a < 4; ++a)
#pragma unroll
    for (int b = 0; b < 4; ++b)
#pragma unroll
      for (int e = 0; e < 4; ++e) accf[a][b][e] = 0.f;

  for (int g = 0; g < NGROUPS; ++g) {
    float s[4];
#pragma unroll
    for (int ni = 0; ni < 4; ++ni)
      s[ni] = sc[g * GN + n0 + wn * 64 + ni * 16 + fr];

    f32x4 accp[4][4];
#pragma unroll
    for (int a = 0; a < 4; ++a)
#pragma unroll
      for (int b = 0; b < 4; ++b)
#pragma unroll
        for (int e = 0; e < 4; ++e) accp[a][b][e] = 0.f;

#pragma unroll
    for (int kk = 0; kk < 4; ++kk) {
      int k0 = g * 128 + kk * 32;
#pragma unroll
      for (int j = 0; j < 2; ++j) {
        int c = c0 + j * 64;
        int row = c >> 2;
        int kp = c & 3;
        size_t goffA = (size_t)(m0 + row) * GK + k0 + kp * 8;
        size_t goffB = (size_t)(n0 + row) * GK + k0 + kp * 8;
        int lo = lds0 + j * 512;
        async16(xh + goffA, sAh + lo);
        async16(xl + goffA, sAl + lo);
        async16(wt + goffB, sB + lo);
      }
      __syncthreads();
      bf16x8 bfr[4];
#pragma unroll
      for (int ni = 0; ni < 4; ++ni)
        bfr[ni] = *(const bf16x8*)&sB[(wn * 64 + ni * 16 + fr) * 32 + fk * 8];
#pragma unroll
      for (int mi = 0; mi < 4; ++mi) {
        int ar = (wm * 64 + mi * 16 + fr) * 32 + fk * 8;
        bf16x8 ah = *(const bf16x8*)&sAh[ar];
        bf16x8 al = *(const bf16x8*)&sAl[ar];
#pragma unroll
        for (int ni = 0; ni < 4; ++ni)
          accp[mi][ni] = __builtin_amdgcn_mfma_f32_16x16x32_bf16(
              ah, bfr[ni], accp[mi][ni], 0, 0, 0);
#pragma unroll
        for (int ni = 0; ni < 4; ++ni)
          accp[mi][ni] = __builtin_amdgcn_mfma_f32_16x16x32_bf16(
              al, bfr[ni], accp[mi][ni], 0, 0, 0);
      }
      __syncthreads();
    }
#pragma unroll
    for (int mi = 0; mi < 4; ++mi)
#pragma unroll
      for (int ni = 0; ni < 4; ++ni)
        accf[mi][ni] += s[ni] * accp[mi][ni];
  }

  // ---- epilogue: fused LoRA (rank-16) + store ----
  f32x4* sax = (f32x4*)sAh;   // 128 rows x 16 f32 = 8KB, reuse A_hi buffer
  f32x4* slb = (f32x4*)sB;
  for (int c = tid; c < 512; c += 256) {
    int row = c >> 2, q = c & 3;
    sax[c] = *(const f32x4*)&axw[(m0 + row) * RLORA + q * 4];
    slb[c] = *(const f32x4*)&lB[(size_t)(n0 + row) * RLORA + q * 4];
  }
  __syncthreads();
  f32x4 lbv[4][4];
#pragma unroll
  for (int ni = 0; ni < 4; ++ni) {
    int nl = wn * 64 + ni * 16 + fr;
#pragma unroll
    for (int q = 0; q < 4; ++q) lbv[ni][q] = slb[nl * 4 + q];
  }
#pragma unroll
  for (int mi = 0; mi < 4; ++mi) {
#pragma unroll
    for (int r = 0; r < 4; ++r) {
      int ml = wm * 64 + mi * 16 + fk * 4 + r;
      f32x4 axq[4];
#pragma unroll
      for (int q = 0; q < 4; ++q) axq[q] = sax[ml * 4 + q];
      float* orow = out + (size_t)(m0 + ml) * GN + n0 + wn * 64;
#pragma unroll
      for (int ni = 0; ni < 4; ++ni) {
        float d = 0.f;
#pragma unroll
        for (int q = 0; q < 4; ++q) {
          f32x4 p = axq[q] * lbv[ni][q];
          d += p[0] + p[1] + p[2] + p[3];
        }
        orow[ni * 16 + fr] = accf[mi][ni][r] + LSCALE * d;
      }
    }
  }
}

// ---------------- fallback path (if ws too small): correct, slow ----------------
__global__ void fb_gemm_k(const float* __restrict__ x, const int* __restrict__ qw,
                          const int* __restrict__ qz, const float* __restrict__ sc,
                          float* __restrict__ out) {
  __shared__ float sx[32][33];
  int nbx = GN / 32;
  int bx = blockIdx.x % nbx, by = blockIdx.x / nbx;
  int tid = threadIdx.x;
  int tn = tid & 31, tg = tid >> 5;
  float acc[4] = {0.f, 0.f, 0.f, 0.f};
  int n = bx * 32 + tn;
  for (int k0 = 0; k0 < GK; k0 += 32) {
    for (int i = tid; i < 32 * 32; i += 256)
      sx[i >> 5][i & 31] = x[(size_t)(by * 32 + (i >> 5)) * GK + k0 + (i & 31)];
    __syncthreads();
    int g = k0 >> 7;
    float z = (float)qz[g * GN + n];
    float s = sc[g * GN + n];
    for (int kk = 0; kk < 32; ++kk) {
      float wv = ((float)qw[(size_t)(k0 + kk) * GN + n] - z) * s;
#pragma unroll
      for (int mm = 0; mm < 4; ++mm) acc[mm] += sx[tg * 4 + mm][kk] * wv;
    }
    __syncthreads();
  }
#pragma unroll
  for (int mm = 0; mm < 4; ++mm)
    out[(size_t)(by * 32 + tg * 4 + mm) * GN + n] = acc[mm];
}

__global__ void fb_lora_k(const float* __restrict__ x, const float* __restrict__ lA,
                          const float* __restrict__ lB, float* __restrict__ out) {
  int m = blockIdx.x;
  int tid = threadIdx.x;
  __shared__ float red[256];
  __shared__ float sax[RLORA];
  for (int r = 0; r < RLORA; ++r) {
    float a = 0.f;
    for (int k = tid; k < GK; k += 256)
      a += x[(size_t)m * GK + k] * lA[(size_t)r * GK + k];
    red[tid] = a;
    __syncthreads();
    for (int off2 = 128; off2 > 0; off2 >>= 1) {
      if (tid < off2) red[tid] += red[tid + off2];
      __syncthreads();
    }
    if (tid == 0) sax[r] = red[0];
    __syncthreads();
  }
  for (int nn = tid; nn < GN; nn += 256) {
    float d = 0.f;
#pragma unroll
    for (int r = 0; r < RLORA; ++r) d += sax[r] * lB[(size_t)nn * RLORA + r];
    out[(size_t)m * GN + nn] += LSCALE * d;
  }
}

extern "C" void kernel_launch(void* const* d_in, const int* in_sizes, int n_in,
                              void* d_out, int out_size, void* d_ws, size_t ws_size,
                              hipStream_t stream) {
  const float* x = (const float*)d_in[0];
  const int* qw = (const int*)d_in[1];
  const int* qz = (const int*)d_in[2];
  const float* sc = (const float*)d_in[3];
  const float* lA = (const float*)d_in[4];
  const float* lB = (const float*)d_in[5];
  float* out = (float*)d_out;

  const size_t XH = 0;
  const size_t XL = (size_t)GM * GK * 2;            // 64 MiB
  const size_t WT = XL * 2;                         // 128 MiB
  const size_t AX = WT + (size_t)GN * GK * 2;       // +32 MiB
  const size_t TOT = AX + (size_t)GM * RLORA * 4;   // +512 KiB = ~160.5 MiB

  if (ws_size >= TOT) {
    uint16_t* xh = (uint16_t*)((char*)d_ws + XH);
    uint16_t* xl = (uint16_t*)((char*)d_ws + XL);
    uint16_t* wt = (uint16_t*)((char*)d_ws + WT);
    float* ax = (float*)((char*)d_ws + AX);
    hipLaunchKernelGGL(prep_x_k, dim3(4096), dim3(256), 0, stream, x, xh, xl);
    hipLaunchKernelGGL(prep_w_k, dim3((GK / 64) * (GN / 64)), dim3(256), 0, stream,
                       qw, qz, wt);
    hipLaunchKernelGGL(lora_ax_k, dim3(GM / 4), dim3(256), 0, stream, x, lA, ax);
    hipLaunchKernelGGL(gemm_k, dim3((GM / 128) * (GN / 128)), dim3(256), 0, stream,
                       xh, xl, wt, sc, ax, lB, out);
  } else {
    hipLaunchKernelGGL(fb_gemm_k, dim3((GM / 32) * (GN / 32)), dim3(256), 0, stream,
                       x, qw, qz, sc, out);
    hipLaunchKernelGGL(fb_lora_k, dim3(GM), dim3(256), 0, stream, x, lA, lB, out);
  }
}

// Round 2
// 739.671 us; speedup vs baseline: 1.4707x; 1.4707x over previous
//
#include <hip/hip_runtime.h>
#include <stdint.h>

// GPTQ (4-bit, group=128) dequant GEMM + rank-16 LoRA, fused epilogue.
// R1: single-pass fp16 MFMA (x fp16, W = (q-z)*s exact-enough in fp16),
// scale folded into W (no per-group accumulator), LDS XOR-swizzle via
// pre-swizzled global_load_lds source (rule #21).

#define GM 8192      // B*S
#define GN 4096      // D_out
#define GK 4096      // D_in
#define RLORA 16
#define LSCALE 2.0f  // lora_alpha / r = 32/16

typedef __attribute__((ext_vector_type(4))) float f32x4;
typedef __attribute__((ext_vector_type(8))) _Float16 half8;
typedef __attribute__((ext_vector_type(8))) uint16_t u16x8;
typedef __attribute__((ext_vector_type(4))) uint16_t u16x4;

__device__ __forceinline__ uint16_t f2h(float f) {
  _Float16 h = (_Float16)f;            // v_cvt_f16_f32, RNE
  union { _Float16 h; uint16_t u; } c;
  c.h = h;
  return c.u;
}

__device__ __forceinline__ void async16(const void* g, void* l) {
  __builtin_amdgcn_global_load_lds(
      (const __attribute__((address_space(1))) void*)g,
      (__attribute__((address_space(3))) void*)l, 16, 0, 0);
}

// ---------------- prepass: x (f32) -> xq (fp16) ----------------
__global__ void prep_x_k(const float* __restrict__ x, uint16_t* __restrict__ xq) {
  const int n4 = GM * GK / 4;
  int stride = gridDim.x * blockDim.x;
  for (int i = blockIdx.x * blockDim.x + threadIdx.x; i < n4; i += stride) {
    f32x4 v = ((const f32x4*)x)[i];
    u16x4 h;
#pragma unroll
    for (int j = 0; j < 4; ++j) h[j] = f2h(v[j]);
    ((u16x4*)xq)[i] = h;
  }
}

// ------- prepass: qweight [K][N] -> WqT [N][K] fp16, value (q-z)*s -------
__global__ void prep_w_k(const int* __restrict__ qw, const int* __restrict__ qz,
                         const float* __restrict__ sc, uint16_t* __restrict__ wt) {
  __shared__ uint16_t t[64][66];   // pad 2 -> conflict-free column reads
  int bn = blockIdx.x % (GN / 64);
  int bk = blockIdx.x / (GN / 64);
  int k0 = bk * 64, n0 = bn * 64;
  int g = k0 >> 7;                 // 64-tile never crosses a 128-group
  int tid = threadIdx.x;
  int n = tid & 63;
  int kb = tid >> 6;               // 0..3
  int z = qz[g * GN + n0 + n];
  float s = sc[g * GN + n0 + n];
#pragma unroll
  for (int i = 0; i < 16; ++i) {
    int kk = kb + i * 4;
    int q = qw[(size_t)(k0 + kk) * GN + n0 + n];
    t[kk][n] = f2h((float)(q - z) * s);
  }
  __syncthreads();
  for (int c = tid; c < 512; c += 256) {
    int nn = c >> 3;
    int k8 = (c & 7) * 8;
    u16x8 v;
#pragma unroll
    for (int j = 0; j < 8; ++j) v[j] = t[k8 + j][nn];
    *(u16x8*)&wt[(size_t)(n0 + nn) * GK + k0 + k8] = v;
  }
}

// ---------------- LoRA: ax[m][r] = sum_k x[m][k] * A[r][k] ----------------
__global__ void lora_ax_k(const float* __restrict__ x, const float* __restrict__ lA,
                          float* __restrict__ ax) {
  int w = threadIdx.x >> 6, lane = threadIdx.x & 63;
  int m = blockIdx.x * 4 + w;
  const float* xr = x + (size_t)m * GK;
  float acc[RLORA];
#pragma unroll
  for (int r = 0; r < RLORA; ++r) acc[r] = 0.f;
  for (int kb = 0; kb < GK; kb += 256) {
    f32x4 xv = *(const f32x4*)&xr[kb + lane * 4];
#pragma unroll
    for (int r = 0; r < RLORA; ++r) {
      f32x4 av = *(const f32x4*)&lA[(size_t)r * GK + kb + lane * 4];
      f32x4 p = xv * av;
      acc[r] += p[0] + p[1] + p[2] + p[3];
    }
  }
#pragma unroll
  for (int r = 0; r < RLORA; ++r) {
#pragma unroll
    for (int off = 32; off > 0; off >>= 1)
      acc[r] += __shfl_xor(acc[r], off);
  }
  if (lane == 0) {
#pragma unroll
    for (int r = 0; r < RLORA; ++r) ax[m * RLORA + r] = acc[r];
  }
}

// ---------------- main GEMM: xq . WqT (fp16 MFMA), LoRA fused ----------------
// LDS tile [128][32] fp16, row stride 64B. XOR-swizzle: phys 16B-chunk
// p = logical_k_chunk ^ ((row>>2)&3)  -> 16 lanes of a b128 read cover all
// 32 banks (addresses mod 256 = 16 distinct multiples of 16).
// global_load_lds writes linearly, so the swizzle is applied on the GLOBAL
// source address (rule #21) and on the ds_read address; LDS stays linear.
__global__ __launch_bounds__(256, 2) void gemm_k(
    const uint16_t* __restrict__ xq, const uint16_t* __restrict__ wt,
    const float* __restrict__ axw, const float* __restrict__ lB,
    float* __restrict__ out) {
  __shared__ __align__(16) uint16_t sA[128 * 32];
  __shared__ __align__(16) uint16_t sB[128 * 32];

  const int nbx = GN / 128;               // 32
  const int nwg = (GM / 128) * nbx;       // 2048 (div by 8 -> simple swizzle ok)
  int wg = blockIdx.x;
  int swz = (wg & 7) * (nwg >> 3) + (wg >> 3);   // XCD-bijective swizzle
  int by = swz / nbx, bx = swz % nbx;
  int m0 = by * 128, n0 = bx * 128;

  int tid = threadIdx.x;
  int w = tid >> 6, lane = tid & 63;
  int wm = w >> 1, wn = w & 1;            // 2x2 wave grid, 64x64 per wave
  int fr = lane & 15, fk = lane >> 4;     // fragment row / k-chunk

  int lds0 = w * 1024;                    // ushort offset of wave's LDS span

  f32x4 acc[4][4];
#pragma unroll
  for (int a = 0; a < 4; ++a)
#pragma unroll
    for (int b = 0; b < 4; ++b)
#pragma unroll
      for (int e = 0; e < 4; ++e) acc[a][b][e] = 0.f;

  for (int k0 = 0; k0 < GK; k0 += 32) {
#pragma unroll
    for (int j = 0; j < 2; ++j) {
      int c = w * 128 + j * 64 + lane;    // dest 16B-slot id within tile
      int row = c >> 2;
      int kl = (c & 3) ^ ((c >> 4) & 3);  // inverse-swizzled logical k-chunk
      size_t goffA = (size_t)(m0 + row) * GK + k0 + kl * 8;
      size_t goffB = (size_t)(n0 + row) * GK + k0 + kl * 8;
      int lo = lds0 + j * 512;
      async16(xq + goffA, sA + lo);
      async16(wt + goffB, sB + lo);
    }
    __syncthreads();
    half8 bfr[4];
#pragma unroll
    for (int ni = 0; ni < 4; ++ni) {
      int row = wn * 64 + ni * 16 + fr;
      bfr[ni] = *(const half8*)&sB[row * 32 + (fk ^ ((row >> 2) & 3)) * 8];
    }
#pragma unroll
    for (int mi = 0; mi < 4; ++mi) {
      int row = wm * 64 + mi * 16 + fr;
      half8 av = *(const half8*)&sA[row * 32 + (fk ^ ((row >> 2) & 3)) * 8];
#pragma unroll
      for (int ni = 0; ni < 4; ++ni)
        acc[mi][ni] = __builtin_amdgcn_mfma_f32_16x16x32_f16(
            av, bfr[ni], acc[mi][ni], 0, 0, 0);
    }
    __syncthreads();
  }

  // ---- epilogue: fused LoRA (rank-16) + store ----
  f32x4* sax = (f32x4*)sA;   // 128 rows x 16 f32 = 8KB, reuse A buffer
  f32x4* slb = (f32x4*)sB;
  for (int c = tid; c < 512; c += 256) {
    int row = c >> 2, q = c & 3;
    sax[c] = *(const f32x4*)&axw[(m0 + row) * RLORA + q * 4];
    slb[c] = *(const f32x4*)&lB[(size_t)(n0 + row) * RLORA + q * 4];
  }
  __syncthreads();
  f32x4 lbv[4][4];
#pragma unroll
  for (int ni = 0; ni < 4; ++ni) {
    int nl = wn * 64 + ni * 16 + fr;
#pragma unroll
    for (int q = 0; q < 4; ++q) lbv[ni][q] = slb[nl * 4 + q];
  }
#pragma unroll
  for (int mi = 0; mi < 4; ++mi) {
#pragma unroll
    for (int r = 0; r < 4; ++r) {
      int ml = wm * 64 + mi * 16 + fk * 4 + r;
      f32x4 axq[4];
#pragma unroll
      for (int q = 0; q < 4; ++q) axq[q] = sax[ml * 4 + q];
      float* orow = out + (size_t)(m0 + ml) * GN + n0 + wn * 64;
#pragma unroll
      for (int ni = 0; ni < 4; ++ni) {
        float d = 0.f;
#pragma unroll
        for (int q = 0; q < 4; ++q) {
          f32x4 p = axq[q] * lbv[ni][q];
          d += p[0] + p[1] + p[2] + p[3];
        }
        orow[ni * 16 + fr] = acc[mi][ni][r] + LSCALE * d;
      }
    }
  }
}

// ---------------- fallback path (if ws too small): correct, slow ----------------
__global__ void fb_gemm_k(const float* __restrict__ x, const int* __restrict__ qw,
                          const int* __restrict__ qz, const float* __restrict__ sc,
                          float* __restrict__ out) {
  __shared__ float sx[32][33];
  int nbx = GN / 32;
  int bx = blockIdx.x % nbx, by = blockIdx.x / nbx;
  int tid = threadIdx.x;
  int tn = tid & 31, tg = tid >> 5;
  float acc[4] = {0.f, 0.f, 0.f, 0.f};
  int n = bx * 32 + tn;
  for (int k0 = 0; k0 < GK; k0 += 32) {
    for (int i = tid; i < 32 * 32; i += 256)
      sx[i >> 5][i & 31] = x[(size_t)(by * 32 + (i >> 5)) * GK + k0 + (i & 31)];
    __syncthreads();
    int g = k0 >> 7;
    float z = (float)qz[g * GN + n];
    float s = sc[g * GN + n];
    for (int kk = 0; kk < 32; ++kk) {
      float wv = ((float)qw[(size_t)(k0 + kk) * GN + n] - z) * s;
#pragma unroll
      for (int mm = 0; mm < 4; ++mm) acc[mm] += sx[tg * 4 + mm][kk] * wv;
    }
    __syncthreads();
  }
#pragma unroll
  for (int mm = 0; mm < 4; ++mm)
    out[(size_t)(by * 32 + tg * 4 + mm) * GN + n] = acc[mm];
}

__global__ void fb_lora_k(const float* __restrict__ x, const float* __restrict__ lA,
                          const float* __restrict__ lB, float* __restrict__ out) {
  int m = blockIdx.x;
  int tid = threadIdx.x;
  __shared__ float red[256];
  __shared__ float sax[RLORA];
  for (int r = 0; r < RLORA; ++r) {
    float a = 0.f;
    for (int k = tid; k < GK; k += 256)
      a += x[(size_t)m * GK + k] * lA[(size_t)r * GK + k];
    red[tid] = a;
    __syncthreads();
    for (int off2 = 128; off2 > 0; off2 >>= 1) {
      if (tid < off2) red[tid] += red[tid + off2];
      __syncthreads();
    }
    if (tid == 0) sax[r] = red[0];
    __syncthreads();
  }
  for (int nn = tid; nn < GN; nn += 256) {
    float d = 0.f;
#pragma unroll
    for (int r = 0; r < RLORA; ++r) d += sax[r] * lB[(size_t)nn * RLORA + r];
    out[(size_t)m * GN + nn] += LSCALE * d;
  }
}

extern "C" void kernel_launch(void* const* d_in, const int* in_sizes, int n_in,
                              void* d_out, int out_size, void* d_ws, size_t ws_size,
                              hipStream_t stream) {
  const float* x = (const float*)d_in[0];
  const int* qw = (const int*)d_in[1];
  const int* qz = (const int*)d_in[2];
  const float* sc = (const float*)d_in[3];
  const float* lA = (const float*)d_in[4];
  const float* lB = (const float*)d_in[5];
  float* out = (float*)d_out;

  const size_t XQ = 0;
  const size_t WT = (size_t)GM * GK * 2;            // 64 MiB
  const size_t AX = WT + (size_t)GN * GK * 2;       // +32 MiB
  const size_t TOT = AX + (size_t)GM * RLORA * 4;   // +512 KiB = ~96.5 MiB

  if (ws_size >= TOT) {
    uint16_t* xq = (uint16_t*)((char*)d_ws + XQ);
    uint16_t* wt = (uint16_t*)((char*)d_ws + WT);
    float* ax = (float*)((char*)d_ws + AX);
    hipLaunchKernelGGL(prep_x_k, dim3(4096), dim3(256), 0, stream, x, xq);
    hipLaunchKernelGGL(prep_w_k, dim3((GK / 64) * (GN / 64)), dim3(256), 0, stream,
                       qw, qz, sc, wt);
    hipLaunchKernelGGL(lora_ax_k, dim3(GM / 4), dim3(256), 0, stream, x, lA, ax);
    hipLaunchKernelGGL(gemm_k, dim3((GM / 128) * (GN / 128)), dim3(256), 0, stream,
                       xq, wt, ax, lB, out);
  } else {
    hipLaunchKernelGGL(fb_gemm_k, dim3((GM / 32) * (GN / 32)), dim3(256), 0, stream,
                       x, qw, qz, sc, out);
    hipLaunchKernelGGL(fb_lora_k, dim3(GM), dim3(256), 0, stream, x, lA, lB, out);
  }
}

// Round 3
// 576.773 us; speedup vs baseline: 1.8861x; 1.2824x over previous
//
#include <hip/hip_runtime.h>
#include <stdint.h>

// GPTQ (4-bit, group=128) dequant GEMM + rank-16 LoRA, fused epilogue.
// R2: 256x256 tile, 8 waves, 4-stage K-slab(32) LDS ring, counted vmcnt(8)
// (never 0 in-loop), raw s_barrier, setprio around MFMA, (row>>1)&3 swizzle.
// Prepass: x->fp16 conversion fused with LoRA ax reduction.

#define GM 8192      // B*S
#define GN 4096      // D_out
#define GK 4096      // D_in
#define RLORA 16
#define LSCALE 2.0f  // lora_alpha / r
#define NSLAB 128    // GK / 32

typedef __attribute__((ext_vector_type(4))) float f32x4;
typedef __attribute__((ext_vector_type(8))) _Float16 half8;
typedef __attribute__((ext_vector_type(8))) uint16_t u16x8;
typedef __attribute__((ext_vector_type(4))) uint16_t u16x4;

#define BAR() asm volatile("s_barrier" ::: "memory")
#define VMCNT8() do { asm volatile("s_waitcnt vmcnt(8)" ::: "memory"); \
                      __builtin_amdgcn_sched_barrier(0); } while (0)
#define VMCNT0() do { asm volatile("s_waitcnt vmcnt(0)" ::: "memory"); \
                      __builtin_amdgcn_sched_barrier(0); } while (0)

__device__ __forceinline__ uint16_t f2h(float f) {
  union { _Float16 h; uint16_t u; } c;
  c.h = (_Float16)f;
  return c.u;
}

__device__ __forceinline__ void async16(const void* g, void* l) {
  __builtin_amdgcn_global_load_lds(
      (const __attribute__((address_space(1))) void*)g,
      (__attribute__((address_space(3))) void*)l, 16, 0, 0);
}

// ---- prepass: x -> xq (fp16) fused with ax[m][r] = sum_k x[m][k]*lA[r][k] ----
__global__ __launch_bounds__(256) void prep_fused_k(
    const float* __restrict__ x, const float* __restrict__ lA,
    uint16_t* __restrict__ xq, float* __restrict__ axw) {
  __shared__ float slA[RLORA][256];
  int tid = threadIdx.x;
  int w = tid >> 6, lane = tid & 63;
  int mb = blockIdx.x * 16;
  float acc[4][RLORA];
#pragma unroll
  for (int i = 0; i < 4; ++i)
#pragma unroll
    for (int r = 0; r < RLORA; ++r) acc[i][r] = 0.f;

  for (int c = 0; c < GK / 256; ++c) {
    {  // stage lA chunk [16][256]
      int r = tid >> 4, seg = tid & 15;
      const f32x4* src = (const f32x4*)&lA[(size_t)r * GK + c * 256 + seg * 16];
      f32x4* dst = (f32x4*)&slA[r][seg * 16];
#pragma unroll
      for (int q = 0; q < 4; ++q) dst[q] = src[q];
    }
    __syncthreads();
#pragma unroll
    for (int i = 0; i < 4; ++i) {
      int m = mb + w * 4 + i;
      f32x4 xv = *(const f32x4*)&x[(size_t)m * GK + c * 256 + lane * 4];
      u16x4 h;
#pragma unroll
      for (int q = 0; q < 4; ++q) h[q] = f2h(xv[q]);
      *(u16x4*)&xq[(size_t)m * GK + c * 256 + lane * 4] = h;
#pragma unroll
      for (int r = 0; r < RLORA; ++r) {
        f32x4 av = *(const f32x4*)&slA[r][lane * 4];
        acc[i][r] += xv[0] * av[0] + xv[1] * av[1] + xv[2] * av[2] + xv[3] * av[3];
      }
    }
    __syncthreads();
  }
#pragma unroll
  for (int i = 0; i < 4; ++i)
#pragma unroll
    for (int r = 0; r < RLORA; ++r) {
      float v = acc[i][r];
#pragma unroll
      for (int off = 32; off > 0; off >>= 1) v += __shfl_xor(v, off);
      if (lane == 0) axw[(size_t)(mb + w * 4 + i) * RLORA + r] = v;
    }
}

// ------- prepass: qweight [K][N] -> WqT [N][K] fp16, value (q-z)*s -------
__global__ void prep_w_k(const int* __restrict__ qw, const int* __restrict__ qz,
                         const float* __restrict__ sc, uint16_t* __restrict__ wt) {
  __shared__ uint16_t t[64][66];
  int bn = blockIdx.x % (GN / 64);
  int bk = blockIdx.x / (GN / 64);
  int k0 = bk * 64, n0 = bn * 64;
  int g = k0 >> 7;
  int tid = threadIdx.x;
  int n = tid & 63;
  int kb = tid >> 6;
  int z = qz[g * GN + n0 + n];
  float s = sc[g * GN + n0 + n];
#pragma unroll
  for (int i = 0; i < 16; ++i) {
    int kk = kb + i * 4;
    int q = qw[(size_t)(k0 + kk) * GN + n0 + n];
    t[kk][n] = f2h((float)(q - z) * s);
  }
  __syncthreads();
  for (int c = tid; c < 512; c += 256) {
    int nn = c >> 3;
    int k8 = (c & 7) * 8;
    u16x8 v;
#pragma unroll
    for (int j = 0; j < 8; ++j) v[j] = t[k8 + j][nn];
    *(u16x8*)&wt[(size_t)(n0 + nn) * GK + k0 + k8] = v;
  }
}

// ---------------- main GEMM: 256x256, 4-stage slab ring, 8 waves ----------------
__global__ __launch_bounds__(512, 2) void gemm_k(
    const uint16_t* __restrict__ xq, const uint16_t* __restrict__ wt,
    const float* __restrict__ axw, const float* __restrict__ lB,
    float* __restrict__ out) {
  __shared__ __align__(16) uint16_t sA[4 * 8192];   // 4 stages x [256][32] fp16
  __shared__ __align__(16) uint16_t sB[4 * 8192];

  const int nbx = GN / 256;                 // 16
  int wg = blockIdx.x;                      // 512 total (div by 8)
  int swz = (wg & 7) * 64 + (wg >> 3);      // XCD-bijective
  int by = swz / nbx, bx = swz % nbx;
  int m0 = by * 256, n0 = bx * 256;

  int tid = threadIdx.x;
  int w = tid >> 6, lane = tid & 63;
  int wm = w >> 2, wn = w & 3;              // 2M x 4N wave grid
  int fr = lane & 15, fk = lane >> 4;

  // staging: per-thread global src (swizzled), wave-uniform LDS dst
  size_t aSrc[2], bSrc[2];
  int dstOff[2];
#pragma unroll
  for (int j = 0; j < 2; ++j) {
    int c = (j * 8 + w) * 64 + lane;        // 16B-chunk id in slab
    int row = c >> 2;
    int kl = (c & 3) ^ ((row >> 1) & 3);    // inverse swizzle on source
    aSrc[j] = (size_t)(m0 + row) * GK + kl * 8;
    bSrc[j] = (size_t)(n0 + row) * GK + kl * 8;
    dstOff[j] = (j * 8 + w) * 512;          // ushort offset, +lane*16B by HW
  }

  // ds_read offsets (swizzled): chunk p = fk ^ ((row>>1)&3)
  int aOff[8], bOff[4];
#pragma unroll
  for (int mi = 0; mi < 8; ++mi) {
    int r = wm * 128 + mi * 16 + fr;
    aOff[mi] = r * 32 + ((fk ^ ((r >> 1) & 3)) << 3);
  }
#pragma unroll
  for (int ni = 0; ni < 4; ++ni) {
    int r = wn * 64 + ni * 16 + fr;
    bOff[ni] = r * 32 + ((fk ^ ((r >> 1) & 3)) << 3);
  }

  // prologue: stage slabs 0,1,2 (order: A,A,B,B per slab -> 4 loads/slab)
#pragma unroll
  for (int t = 0; t < 3; ++t) {
    async16(xq + aSrc[0] + t * 32, sA + t * 8192 + dstOff[0]);
    async16(xq + aSrc[1] + t * 32, sA + t * 8192 + dstOff[1]);
    async16(wt + bSrc[0] + t * 32, sB + t * 8192 + dstOff[0]);
    async16(wt + bSrc[1] + t * 32, sB + t * 8192 + dstOff[1]);
  }

  f32x4 acc[8][4];
#pragma unroll
  for (int a = 0; a < 8; ++a)
#pragma unroll
    for (int b = 0; b < 4; ++b)
#pragma unroll
      for (int e = 0; e < 4; ++e) acc[a][b][e] = 0.f;

  VMCNT8();   // slab 0 landed (12 issued - 8 = first 4 loads)
  BAR();

#pragma unroll 4
  for (int g = 0; g < NSLAB; ++g) {
    const uint16_t* sa = sA + (g & 3) * 8192;
    const uint16_t* sb = sB + (g & 3) * 8192;
    int t2 = g + 3;
    int tc = (t2 < NSLAB ? t2 : NSLAB - 1) * 32;  // dummy re-stage at tail
    uint16_t* dA = sA + (t2 & 3) * 8192;
    uint16_t* dB = sB + (t2 & 3) * 8192;

    // ---- phase 0: read A0-3 + B0-3, stage A(g+3), MFMA mi 0..3 ----
    half8 b0[4], a0[4];
#pragma unroll
    for (int ni = 0; ni < 4; ++ni) b0[ni] = *(const half8*)(sb + bOff[ni]);
#pragma unroll
    for (int mi = 0; mi < 4; ++mi) a0[mi] = *(const half8*)(sa + aOff[mi]);
    async16(xq + aSrc[0] + tc, dA + dstOff[0]);
    async16(xq + aSrc[1] + tc, dA + dstOff[1]);
    BAR();
    __builtin_amdgcn_s_setprio(1);
    __builtin_amdgcn_sched_barrier(0);
#pragma unroll
    for (int mi = 0; mi < 4; ++mi)
#pragma unroll
      for (int ni = 0; ni < 4; ++ni)
        acc[mi][ni] = __builtin_amdgcn_mfma_f32_16x16x32_f16(
            a0[mi], b0[ni], acc[mi][ni], 0, 0, 0);
    __builtin_amdgcn_sched_barrier(0);
    __builtin_amdgcn_s_setprio(0);
    BAR();

    // ---- phase 1: read A4-7, stage B(g+3), vmcnt(8), MFMA mi 4..7 ----
    half8 a1[4];
#pragma unroll
    for (int mi = 0; mi < 4; ++mi) a1[mi] = *(const half8*)(sa + aOff[4 + mi]);
    async16(wt + bSrc[0] + tc, dB + dstOff[0]);
    async16(wt + bSrc[1] + tc, dB + dstOff[1]);
    VMCNT8();   // slab g+1 landed (2 slabs = 8 loads allowed in flight)
    BAR();
    __builtin_amdgcn_s_setprio(1);
    __builtin_amdgcn_sched_barrier(0);
#pragma unroll
    for (int mi = 0; mi < 4; ++mi)
#pragma unroll
      for (int ni = 0; ni < 4; ++ni)
        acc[4 + mi][ni] = __builtin_amdgcn_mfma_f32_16x16x32_f16(
            a1[mi], b0[ni], acc[4 + mi][ni], 0, 0, 0);
    __builtin_amdgcn_sched_barrier(0);
    __builtin_amdgcn_s_setprio(0);
    BAR();
  }

  // ---- epilogue: drain, stage ax/lB blocks, fused LoRA + store ----
  VMCNT0();
  __syncthreads();
  float* sax = (float*)sA;    // [256][16] f32
  float* slb = (float*)sB;    // [256][16] f32
  for (int c = tid; c < 1024; c += 512) {
    int row = c >> 2, q = c & 3;
    ((f32x4*)sax)[c] = *(const f32x4*)&axw[(size_t)(m0 + row) * RLORA + q * 4];
    ((f32x4*)slb)[c] = *(const f32x4*)&lB[(size_t)(n0 + row) * RLORA + q * 4];
  }
  __syncthreads();
  f32x4 lbv[4][4];
#pragma unroll
  for (int ni = 0; ni < 4; ++ni) {
    int nl = wn * 64 + ni * 16 + fr;
#pragma unroll
    for (int q = 0; q < 4; ++q) lbv[ni][q] = ((const f32x4*)&slb[nl * 16])[q];
  }
#pragma unroll
  for (int mi = 0; mi < 8; ++mi) {
#pragma unroll
    for (int e = 0; e < 4; ++e) {
      int mr = wm * 128 + mi * 16 + fk * 4 + e;
      f32x4 axq[4];
#pragma unroll
      for (int q = 0; q < 4; ++q) axq[q] = ((const f32x4*)&sax[mr * 16])[q];
      float* orow = out + (size_t)(m0 + mr) * GN + n0 + wn * 64;
#pragma unroll
      for (int ni = 0; ni < 4; ++ni) {
        float d = 0.f;
#pragma unroll
        for (int q = 0; q < 4; ++q) {
          f32x4 p = axq[q] * lbv[ni][q];
          d += p[0] + p[1] + p[2] + p[3];
        }
        orow[ni * 16 + fr] = acc[mi][ni][e] + LSCALE * d;
      }
    }
  }
}

// ---------------- fallback path (if ws too small): correct, slow ----------------
__global__ void fb_gemm_k(const float* __restrict__ x, const int* __restrict__ qw,
                          const int* __restrict__ qz, const float* __restrict__ sc,
                          float* __restrict__ out) {
  __shared__ float sx[32][33];
  int nbx = GN / 32;
  int bx = blockIdx.x % nbx, by = blockIdx.x / nbx;
  int tid = threadIdx.x;
  int tn = tid & 31, tg = tid >> 5;
  float acc[4] = {0.f, 0.f, 0.f, 0.f};
  int n = bx * 32 + tn;
  for (int k0 = 0; k0 < GK; k0 += 32) {
    for (int i = tid; i < 32 * 32; i += 256)
      sx[i >> 5][i & 31] = x[(size_t)(by * 32 + (i >> 5)) * GK + k0 + (i & 31)];
    __syncthreads();
    int g = k0 >> 7;
    float z = (float)qz[g * GN + n];
    float s = sc[g * GN + n];
    for (int kk = 0; kk < 32; ++kk) {
      float wv = ((float)qw[(size_t)(k0 + kk) * GN + n] - z) * s;
#pragma unroll
      for (int mm = 0; mm < 4; ++mm) acc[mm] += sx[tg * 4 + mm][kk] * wv;
    }
    __syncthreads();
  }
#pragma unroll
  for (int mm = 0; mm < 4; ++mm)
    out[(size_t)(by * 32 + tg * 4 + mm) * GN + n] = acc[mm];
}

__global__ void fb_lora_k(const float* __restrict__ x, const float* __restrict__ lA,
                          const float* __restrict__ lB, float* __restrict__ out) {
  int m = blockIdx.x;
  int tid = threadIdx.x;
  __shared__ float red[256];
  __shared__ float sax[RLORA];
  for (int r = 0; r < RLORA; ++r) {
    float a = 0.f;
    for (int k = tid; k < GK; k += 256)
      a += x[(size_t)m * GK + k] * lA[(size_t)r * GK + k];
    red[tid] = a;
    __syncthreads();
    for (int off2 = 128; off2 > 0; off2 >>= 1) {
      if (tid < off2) red[tid] += red[tid + off2];
      __syncthreads();
    }
    if (tid == 0) sax[r] = red[0];
    __syncthreads();
  }
  for (int nn = tid; nn < GN; nn += 256) {
    float d = 0.f;
#pragma unroll
    for (int r = 0; r < RLORA; ++r) d += sax[r] * lB[(size_t)nn * RLORA + r];
    out[(size_t)m * GN + nn] += LSCALE * d;
  }
}

extern "C" void kernel_launch(void* const* d_in, const int* in_sizes, int n_in,
                              void* d_out, int out_size, void* d_ws, size_t ws_size,
                              hipStream_t stream) {
  const float* x = (const float*)d_in[0];
  const int* qw = (const int*)d_in[1];
  const int* qz = (const int*)d_in[2];
  const float* sc = (const float*)d_in[3];
  const float* lA = (const float*)d_in[4];
  const float* lB = (const float*)d_in[5];
  float* out = (float*)d_out;

  const size_t XQ = 0;
  const size_t WT = (size_t)GM * GK * 2;            // 64 MiB
  const size_t AX = WT + (size_t)GN * GK * 2;       // +32 MiB
  const size_t TOT = AX + (size_t)GM * RLORA * 4;   // ~96.5 MiB

  if (ws_size >= TOT) {
    uint16_t* xq = (uint16_t*)((char*)d_ws + XQ);
    uint16_t* wt = (uint16_t*)((char*)d_ws + WT);
    float* ax = (float*)((char*)d_ws + AX);
    hipLaunchKernelGGL(prep_fused_k, dim3(GM / 16), dim3(256), 0, stream,
                       x, lA, xq, ax);
    hipLaunchKernelGGL(prep_w_k, dim3((GK / 64) * (GN / 64)), dim3(256), 0, stream,
                       qw, qz, sc, wt);
    hipLaunchKernelGGL(gemm_k, dim3((GM / 256) * (GN / 256)), dim3(512), 0, stream,
                       xq, wt, ax, lB, out);
  } else {
    hipLaunchKernelGGL(fb_gemm_k, dim3((GM / 32) * (GN / 32)), dim3(256), 0, stream,
                       x, qw, qz, sc, out);
    hipLaunchKernelGGL(fb_lora_k, dim3(GM), dim3(256), 0, stream, x, lA, lB, out);
  }
}

// Round 4
// 546.193 us; speedup vs baseline: 1.9917x; 1.0560x over previous
//
#include <hip/hip_runtime.h>
#include <stdint.h>

// GPTQ (4-bit, group=128) dequant GEMM + rank-16 LoRA, fused epilogue.
// R3: (a) LoRA ax moved to MFMA, fused with x->fp16 conversion (same-wave
// write->read); (b) gemm ring relaxed to ONE barrier per K-32 group
// (hazard-analyzed: reads complete before group-end barrier; stages target
// buffer (g-1)&3 whose reads finished a barrier ago), sched_barrier walls
// removed so phase-1 ds_reads hoist into phase-0 MFMA cluster.

#define GM 8192      // B*S
#define GN 4096      // D_out
#define GK 4096      // D_in
#define RLORA 16
#define LSCALE 2.0f  // lora_alpha / r
#define NSLAB 128    // GK / 32

typedef __attribute__((ext_vector_type(4))) float f32x4;
typedef __attribute__((ext_vector_type(8))) _Float16 half8;
typedef __attribute__((ext_vector_type(8))) uint16_t u16x8;
typedef __attribute__((ext_vector_type(4))) uint16_t u16x4;

#define BAR() asm volatile("s_barrier" ::: "memory")
#define VMCNT8() do { asm volatile("s_waitcnt vmcnt(8)" ::: "memory"); \
                      __builtin_amdgcn_sched_barrier(0); } while (0)
#define VMCNT0() do { asm volatile("s_waitcnt vmcnt(0)" ::: "memory"); \
                      __builtin_amdgcn_sched_barrier(0); } while (0)

__device__ __forceinline__ uint16_t f2h(float f) {
  union { _Float16 h; uint16_t u; } c;
  c.h = (_Float16)f;
  return c.u;
}

__device__ __forceinline__ void async16(const void* g, void* l) {
  __builtin_amdgcn_global_load_lds(
      (const __attribute__((address_space(1))) void*)g,
      (__attribute__((address_space(3))) void*)l, 16, 0, 0);
}

// ---- prepass 1: qweight [K][N] -> WqT [N][K] fp16 ((q-z)*s); +lA -> fp16 ----
__global__ void prep_w_k(const int* __restrict__ qw, const int* __restrict__ qz,
                         const float* __restrict__ sc, const float* __restrict__ lA,
                         uint16_t* __restrict__ wt, uint16_t* __restrict__ laq) {
  int tid = threadIdx.x;
  if (blockIdx.x >= (GK / 64) * (GN / 64)) {
    // lA conversion: 16*4096 f32 -> fp16, 2 blocks x 256 threads x 32 chunks
    int b = blockIdx.x - (GK / 64) * (GN / 64);
#pragma unroll
    for (int i = 0; i < 32; ++i) {
      int c = b * 8192 + i * 256 + tid;   // f32x4 chunk id, 0..16383
      f32x4 v = ((const f32x4*)lA)[c];
      u16x4 h;
#pragma unroll
      for (int q = 0; q < 4; ++q) h[q] = f2h(v[q]);
      ((u16x4*)laq)[c] = h;
    }
    return;
  }
  __shared__ uint16_t t[64][66];
  int bn = blockIdx.x % (GN / 64);
  int bk = blockIdx.x / (GN / 64);
  int k0 = bk * 64, n0 = bn * 64;
  int g = k0 >> 7;
  int n = tid & 63;
  int kb = tid >> 6;
  int z = qz[g * GN + n0 + n];
  float s = sc[g * GN + n0 + n];
#pragma unroll
  for (int i = 0; i < 16; ++i) {
    int kk = kb + i * 4;
    int q = qw[(size_t)(k0 + kk) * GN + n0 + n];
    t[kk][n] = f2h((float)(q - z) * s);
  }
  __syncthreads();
  for (int c = tid; c < 512; c += 256) {
    int nn = c >> 3;
    int k8 = (c & 7) * 8;
    u16x8 v;
#pragma unroll
    for (int j = 0; j < 8; ++j) v[j] = t[k8 + j][nn];
    *(u16x8*)&wt[(size_t)(n0 + nn) * GK + k0 + k8] = v;
  }
}

// ---- prepass 2: x -> xq (fp16) + ax = xq . laq^T via MFMA ----
// Wave w converts rows [m0,m0+16) x K-quarter w, then MFMAs its own freshly
// written quarter (same-wave write->read, vmcnt(0) ordered). LDS reduce.
__global__ __launch_bounds__(256) void prep_xax_k(
    const float* __restrict__ x, const uint16_t* __restrict__ laq,
    uint16_t* __restrict__ xq, float* __restrict__ axw) {
  __shared__ float red[4][16][17];
  int tid = threadIdx.x;
  int w = tid >> 6, lane = tid & 63;
  int m0 = blockIdx.x * 16;
  int kq = w * 1024;
  // phase A: convert 16 rows x 1024 k (coalesced 1KB bursts per wave)
#pragma unroll
  for (int i = 0; i < 16; ++i) {
#pragma unroll
    for (int j = 0; j < 4; ++j) {
      size_t off = (size_t)(m0 + i) * GK + kq + j * 256 + lane * 4;
      f32x4 v = *(const f32x4*)&x[off];
      u16x4 h;
#pragma unroll
      for (int q = 0; q < 4; ++q) h[q] = f2h(v[q]);
      *(u16x4*)&xq[off] = h;
    }
  }
  VMCNT0();   // own stores complete before re-reading
  // phase B: 32 slabs of K=32, one 16x16x32 MFMA each
  int fr = lane & 15, fk = lane >> 4;
  f32x4 acc = {0.f, 0.f, 0.f, 0.f};
  const uint16_t* xrow = xq + (size_t)(m0 + fr) * GK + kq + fk * 8;
  const uint16_t* arow = laq + (size_t)fr * GK + kq + fk * 8;
#pragma unroll 4
  for (int s = 0; s < 32; ++s) {
    half8 av = *(const half8*)(xrow + s * 32);
    half8 bv = *(const half8*)(arow + s * 32);
    acc = __builtin_amdgcn_mfma_f32_16x16x32_f16(av, bv, acc, 0, 0, 0);
  }
  // C layout: col(=r) = lane&15, row(=m) = fk*4+e
#pragma unroll
  for (int e = 0; e < 4; ++e) red[w][fk * 4 + e][fr] = acc[e];
  __syncthreads();
  int row = tid >> 4, col = tid & 15;
  if (tid < 256) {
    float sum = red[0][row][col] + red[1][row][col] +
                red[2][row][col] + red[3][row][col];
    axw[(size_t)(m0 + row) * RLORA + col] = sum;
  }
}

// ---------------- main GEMM: 256x256, 4-stage slab ring, 8 waves ----------------
__global__ __launch_bounds__(512, 2) void gemm_k(
    const uint16_t* __restrict__ xq, const uint16_t* __restrict__ wt,
    const float* __restrict__ axw, const float* __restrict__ lB,
    float* __restrict__ out) {
  __shared__ __align__(16) uint16_t sA[4 * 8192];   // 4 stages x [256][32] fp16
  __shared__ __align__(16) uint16_t sB[4 * 8192];

  const int nbx = GN / 256;                 // 16
  int wg = blockIdx.x;                      // 512 total (div by 8)
  int swz = (wg & 7) * 64 + (wg >> 3);      // XCD-bijective
  int by = swz / nbx, bx = swz % nbx;
  int m0 = by * 256, n0 = bx * 256;

  int tid = threadIdx.x;
  int w = tid >> 6, lane = tid & 63;
  int wm = w >> 2, wn = w & 3;              // 2M x 4N wave grid
  int fr = lane & 15, fk = lane >> 4;

  // staging: per-thread global src (inverse-swizzled), wave-uniform LDS dst
  size_t aSrc[2], bSrc[2];
  int dstOff[2];
#pragma unroll
  for (int j = 0; j < 2; ++j) {
    int c = (j * 8 + w) * 64 + lane;        // 16B-chunk id in slab
    int row = c >> 2;
    int kl = (c & 3) ^ ((row >> 1) & 3);
    aSrc[j] = (size_t)(m0 + row) * GK + kl * 8;
    bSrc[j] = (size_t)(n0 + row) * GK + kl * 8;
    dstOff[j] = (j * 8 + w) * 512;
  }

  // ds_read offsets (swizzled): chunk p = fk ^ ((row>>1)&3)
  int aOff[8], bOff[4];
#pragma unroll
  for (int mi = 0; mi < 8; ++mi) {
    int r = wm * 128 + mi * 16 + fr;
    aOff[mi] = r * 32 + ((fk ^ ((r >> 1) & 3)) << 3);
  }
#pragma unroll
  for (int ni = 0; ni < 4; ++ni) {
    int r = wn * 64 + ni * 16 + fr;
    bOff[ni] = r * 32 + ((fk ^ ((r >> 1) & 3)) << 3);
  }

  // prologue: stage slabs 0,1,2
#pragma unroll
  for (int t = 0; t < 3; ++t) {
    async16(xq + aSrc[0] + t * 32, sA + t * 8192 + dstOff[0]);
    async16(xq + aSrc[1] + t * 32, sA + t * 8192 + dstOff[1]);
    async16(wt + bSrc[0] + t * 32, sB + t * 8192 + dstOff[0]);
    async16(wt + bSrc[1] + t * 32, sB + t * 8192 + dstOff[1]);
  }

  f32x4 acc[8][4];
#pragma unroll
  for (int a = 0; a < 8; ++a)
#pragma unroll
    for (int b = 0; b < 4; ++b)
#pragma unroll
      for (int e = 0; e < 4; ++e) acc[a][b][e] = 0.f;

  VMCNT8();   // slab 0 landed
  BAR();

#pragma unroll 4
  for (int g = 0; g < NSLAB; ++g) {
    const uint16_t* sa = sA + (g & 3) * 8192;
    const uint16_t* sb = sB + (g & 3) * 8192;
    int t2 = g + 3;
    int tc = (t2 < NSLAB ? t2 : NSLAB - 1) * 32;  // dummy re-stage at tail
    uint16_t* dA = sA + (t2 & 3) * 8192;
    uint16_t* dB = sB + (t2 & 3) * 8192;

    // phase 0: read A0-3 + B0-3, stage A(g+3), MFMA mi 0..3
    half8 b0[4], a0[4];
#pragma unroll
    for (int ni = 0; ni < 4; ++ni) b0[ni] = *(const half8*)(sb + bOff[ni]);
#pragma unroll
    for (int mi = 0; mi < 4; ++mi) a0[mi] = *(const half8*)(sa + aOff[mi]);
    async16(xq + aSrc[0] + tc, dA + dstOff[0]);
    async16(xq + aSrc[1] + tc, dA + dstOff[1]);
    __builtin_amdgcn_s_setprio(1);
#pragma unroll
    for (int mi = 0; mi < 4; ++mi)
#pragma unroll
      for (int ni = 0; ni < 4; ++ni)
        acc[mi][ni] = __builtin_amdgcn_mfma_f32_16x16x32_f16(
            a0[mi], b0[ni], acc[mi][ni], 0, 0, 0);
    __builtin_amdgcn_s_setprio(0);

    // phase 1: read A4-7, stage B(g+3), counted vmcnt, MFMA mi 4..7
    half8 a1[4];
#pragma unroll
    for (int mi = 0; mi < 4; ++mi) a1[mi] = *(const half8*)(sa + aOff[4 + mi]);
    async16(wt + bSrc[0] + tc, dB + dstOff[0]);
    async16(wt + bSrc[1] + tc, dB + dstOff[1]);
    VMCNT8();   // slab g+1 resident before next group
    __builtin_amdgcn_s_setprio(1);
#pragma unroll
    for (int mi = 0; mi < 4; ++mi)
#pragma unroll
      for (int ni = 0; ni < 4; ++ni)
        acc[4 + mi][ni] = __builtin_amdgcn_mfma_f32_16x16x32_f16(
            a1[mi], b0[ni], acc[4 + mi][ni], 0, 0, 0);
    __builtin_amdgcn_s_setprio(0);
    BAR();      // single barrier per group: frees buffer (g)&3 for reuse
  }

  // ---- epilogue: drain own DMA, then block-wide barrier, LoRA + store ----
  VMCNT0();
  __syncthreads();
  float* sax = (float*)sA;    // [256][16] f32 = 16KB (buffer 0)
  float* slb = (float*)sB;
  for (int c = tid; c < 1024; c += 512) {
    int row = c >> 2, q = c & 3;
    ((f32x4*)sax)[c] = *(const f32x4*)&axw[(size_t)(m0 + row) * RLORA + q * 4];
    ((f32x4*)slb)[c] = *(const f32x4*)&lB[(size_t)(n0 + row) * RLORA + q * 4];
  }
  __syncthreads();
  f32x4 lbv[4][4];
#pragma unroll
  for (int ni = 0; ni < 4; ++ni) {
    int nl = wn * 64 + ni * 16 + fr;
#pragma unroll
    for (int q = 0; q < 4; ++q) lbv[ni][q] = ((const f32x4*)&slb[nl * 16])[q];
  }
#pragma unroll
  for (int mi = 0; mi < 8; ++mi) {
#pragma unroll
    for (int e = 0; e < 4; ++e) {
      int mr = wm * 128 + mi * 16 + fk * 4 + e;
      f32x4 axq[4];
#pragma unroll
      for (int q = 0; q < 4; ++q) axq[q] = ((const f32x4*)&sax[mr * 16])[q];
      float* orow = out + (size_t)(m0 + mr) * GN + n0 + wn * 64;
#pragma unroll
      for (int ni = 0; ni < 4; ++ni) {
        float d = 0.f;
#pragma unroll
        for (int q = 0; q < 4; ++q) {
          f32x4 p = axq[q] * lbv[ni][q];
          d += p[0] + p[1] + p[2] + p[3];
        }
        orow[ni * 16 + fr] = acc[mi][ni][e] + LSCALE * d;
      }
    }
  }
}

// ---------------- fallback path (if ws too small): correct, slow ----------------
__global__ void fb_gemm_k(const float* __restrict__ x, const int* __restrict__ qw,
                          const int* __restrict__ qz, const float* __restrict__ sc,
                          float* __restrict__ out) {
  __shared__ float sx[32][33];
  int nbx = GN / 32;
  int bx = blockIdx.x % nbx, by = blockIdx.x / nbx;
  int tid = threadIdx.x;
  int tn = tid & 31, tg = tid >> 5;
  float acc[4] = {0.f, 0.f, 0.f, 0.f};
  int n = bx * 32 + tn;
  for (int k0 = 0; k0 < GK; k0 += 32) {
    for (int i = tid; i < 32 * 32; i += 256)
      sx[i >> 5][i & 31] = x[(size_t)(by * 32 + (i >> 5)) * GK + k0 + (i & 31)];
    __syncthreads();
    int g = k0 >> 7;
    float z = (float)qz[g * GN + n];
    float s = sc[g * GN + n];
    for (int kk = 0; kk < 32; ++kk) {
      float wv = ((float)qw[(size_t)(k0 + kk) * GN + n] - z) * s;
#pragma unroll
      for (int mm = 0; mm < 4; ++mm) acc[mm] += sx[tg * 4 + mm][kk] * wv;
    }
    __syncthreads();
  }
#pragma unroll
  for (int mm = 0; mm < 4; ++mm)
    out[(size_t)(by * 32 + tg * 4 + mm) * GN + n] = acc[mm];
}

__global__ void fb_lora_k(const float* __restrict__ x, const float* __restrict__ lA,
                          const float* __restrict__ lB, float* __restrict__ out) {
  int m = blockIdx.x;
  int tid = threadIdx.x;
  __shared__ float red[256];
  __shared__ float sax[RLORA];
  for (int r = 0; r < RLORA; ++r) {
    float a = 0.f;
    for (int k = tid; k < GK; k += 256)
      a += x[(size_t)m * GK + k] * lA[(size_t)r * GK + k];
    red[tid] = a;
    __syncthreads();
    for (int off2 = 128; off2 > 0; off2 >>= 1) {
      if (tid < off2) red[tid] += red[tid + off2];
      __syncthreads();
    }
    if (tid == 0) sax[r] = red[0];
    __syncthreads();
  }
  for (int nn = tid; nn < GN; nn += 256) {
    float d = 0.f;
#pragma unroll
    for (int r = 0; r < RLORA; ++r) d += sax[r] * lB[(size_t)nn * RLORA + r];
    out[(size_t)m * GN + nn] += LSCALE * d;
  }
}

extern "C" void kernel_launch(void* const* d_in, const int* in_sizes, int n_in,
                              void* d_out, int out_size, void* d_ws, size_t ws_size,
                              hipStream_t stream) {
  const float* x = (const float*)d_in[0];
  const int* qw = (const int*)d_in[1];
  const int* qz = (const int*)d_in[2];
  const float* sc = (const float*)d_in[3];
  const float* lA = (const float*)d_in[4];
  const float* lB = (const float*)d_in[5];
  float* out = (float*)d_out;

  const size_t XQ = 0;
  const size_t WT = (size_t)GM * GK * 2;                 // 64 MiB
  const size_t AX = WT + (size_t)GN * GK * 2;            // +32 MiB
  const size_t LQ = AX + (size_t)GM * RLORA * 4;         // +512 KiB
  const size_t TOT = LQ + (size_t)RLORA * GK * 2;        // +128 KiB

  if (ws_size >= TOT) {
    uint16_t* xq = (uint16_t*)((char*)d_ws + XQ);
    uint16_t* wt = (uint16_t*)((char*)d_ws + WT);
    float* ax = (float*)((char*)d_ws + AX);
    uint16_t* laq = (uint16_t*)((char*)d_ws + LQ);
    hipLaunchKernelGGL(prep_w_k, dim3((GK / 64) * (GN / 64) + 2), dim3(256), 0,
                       stream, qw, qz, sc, lA, wt, laq);
    hipLaunchKernelGGL(prep_xax_k, dim3(GM / 16), dim3(256), 0, stream,
                       x, laq, xq, ax);
    hipLaunchKernelGGL(gemm_k, dim3((GM / 256) * (GN / 256)), dim3(512), 0, stream,
                       xq, wt, ax, lB, out);
  } else {
    hipLaunchKernelGGL(fb_gemm_k, dim3((GM / 32) * (GN / 32)), dim3(256), 0, stream,
                       x, qw, qz, sc, out);
    hipLaunchKernelGGL(fb_lora_k, dim3(GM), dim3(256), 0, stream, x, lA, lB, out);
  }
}